// Round 1
// baseline (1151.399 us; speedup 1.0000x reference)
//
#include <hip/hip_runtime.h>
#include <math.h>

#define NB    16
#define CIx   256
#define COx   128
#define NPTS  2000
#define KW    9
#define NKx   18000   // NPTS*KW

// ---------------- stats over x_local: per (b,i) sum/sumsq over 18000 ----------------
__global__ __launch_bounds__(256) void k_xstats(const float* __restrict__ xl,
    float* __restrict__ sum, float* __restrict__ sumsq){
  int bi = blockIdx.x;                       // b*256 + i
  const float4* p = (const float4*)(xl + (size_t)bi * NKx);
  float s = 0.f, ss = 0.f;
  for (int idx = threadIdx.x; idx < NKx/4; idx += 256){
    float4 v = p[idx];
    s  += v.x + v.y + v.z + v.w;
    ss += v.x*v.x + v.y*v.y + v.z*v.z + v.w*v.w;
  }
  __shared__ float rs[256], rss[256];
  rs[threadIdx.x] = s; rss[threadIdx.x] = ss;
  __syncthreads();
  for (int off = 128; off > 0; off >>= 1){
    if (threadIdx.x < off){ rs[threadIdx.x] += rs[threadIdx.x+off]; rss[threadIdx.x] += rss[threadIdx.x+off]; }
    __syncthreads();
  }
  if (threadIdx.x == 0){ sum[bi] = rs[0]; sumsq[bi] = rss[0]; }
}

// inorm(1e-3) + bnorm(1e-5) collapse: per (b,i) m and combined scale s
__global__ void k_xscale(const float* __restrict__ sum, const float* __restrict__ sumsq,
                         float* __restrict__ mOut, float* __restrict__ sOut){
  int i = threadIdx.x;                       // channel 0..255
  float vl[NB], ml[NB];
  float V = 0.f;
  for (int b = 0; b < NB; b++){
    int bi = b*CIx + i;
    float m = sum[bi] * (1.f/(float)NKx);
    float v = sumsq[bi] * (1.f/(float)NKx) - m*m;
    ml[b] = m; vl[b] = v;
    V += v / (v + 1e-3f);
  }
  V *= (1.f/(float)NB);
  float bs = rsqrtf(V + 1e-5f);
  for (int b = 0; b < NB; b++){
    int bi = b*CIx + i;
    mOut[bi] = ml[b];
    sOut[bi] = rsqrtf(vl[b] + 1e-3f) * bs;
  }
}

// ---------------- fold wk@w_att1 / wv@w_att1 into WT_kv[i][r] (r<128:K, r>=128:V) ----------------
__global__ void k_prep_kv(const float* __restrict__ w_att1, const float* __restrict__ wk,
                          const float* __restrict__ wv, const float* __restrict__ b_att1,
                          const float* __restrict__ bk, const float* __restrict__ bv,
                          float* __restrict__ WT, float* __restrict__ bKV){
  int r = blockIdx.x;   // 0..255
  int i = threadIdx.x;  // 0..255
  const float* wr = (r < 128) ? (wk + r*128) : (wv + (r-128)*128);
  float acc = 0.f;
  for (int c = 0; c < 128; c++) acc += wr[c] * w_att1[c*CIx + i];
  WT[i*256 + r] = acc;
  if (i == 0){
    float bacc = (r < 128) ? bk[r] : bv[r-128];
    for (int c = 0; c < 128; c++) bacc += wr[c] * b_att1[c];
    bKV[r] = bacc;
  }
}

// generic transpose: out[i*R + r] = in[r*I + i]
__global__ void k_transpose(const float* __restrict__ in, float* __restrict__ out, int R, int I){
  int idx = blockIdx.x*256 + threadIdx.x;
  if (idx < R*I){ int r = idx / I; int i = idx - r*I; out[i*R + r] = in[idx]; }
}

// pack [w_right; w_l1] transposed: WT2[i][r]
__global__ void k_prep2(const float* __restrict__ w_right, const float* __restrict__ w_l1,
                        const float* __restrict__ b_right, const float* __restrict__ b_l1,
                        float* __restrict__ WT2, float* __restrict__ bias2){
  int r = blockIdx.x; int i = threadIdx.x;
  const float* w = (r < 128) ? (w_right + r*CIx) : (w_l1 + (r-128)*CIx);
  WT2[i*256 + r] = w[i];
  if (i == 0) bias2[r] = (r < 128) ? b_right[r] : b_l1[r-128];
}

// ---------------- main fused kernel: normalize -> KV GEMM -> q -> softmax -> PV ----------------
__global__ __launch_bounds__(256) void k_attn(
    const float* __restrict__ xl, const float* __restrict__ x_row,
    const float* __restrict__ mArr, const float* __restrict__ sArr,
    const float* __restrict__ WT, const float* __restrict__ bKV,
    const float* __restrict__ wqT, const float* __restrict__ bq,
    float* __restrict__ out_local)
{
  const int b  = blockIdx.y;
  const int n0 = blockIdx.x * 8;             // 8 n-points per block, 72 cols (n,k)
  const int tid = threadIdx.x;
  __shared__ float t_lds[128][72];
  __shared__ float xr[128][8];

  if (tid < 128){
    const float* src = x_row + ((size_t)b*COx + tid)*NPTS + n0;
    float4 a = *(const float4*)src;
    float4 c4 = *(const float4*)(src + 4);
    xr[tid][0]=a.x; xr[tid][1]=a.y; xr[tid][2]=a.z; xr[tid][3]=a.w;
    xr[tid][4]=c4.x; xr[tid][5]=c4.y; xr[tid][6]=c4.z; xr[tid][7]=c4.w;
  }

  const int c    = tid & 127;                // channel
  const int half = tid >> 7;                 // col half: 0 -> cols 0..35, 1 -> 36..71
  const int c0   = half * 36;

  float accK[36], accV[36];
#pragma unroll
  for (int j = 0; j < 36; j++){ accK[j] = 0.f; accV[j] = 0.f; }

  for (int chunk = 0; chunk < 2; chunk++){
    __syncthreads();
    // load + normalize 128 input rows x 72 cols
    for (int idx = tid; idx < 128*72; idx += 256){
      int i = idx / 72; int cc = idx - i*72;
      int gi = chunk*128 + i;
      float v = xl[(size_t)b*CIx*NKx + (size_t)gi*NKx + n0*KW + cc];
      t_lds[i][cc] = fmaxf((v - mArr[b*CIx + gi]) * sArr[b*CIx + gi], 0.f);
    }
    __syncthreads();
#pragma unroll 4
    for (int i = 0; i < 128; i++){
      float wk_ = WT[(chunk*128 + i)*256 + c];
      float wv_ = WT[(chunk*128 + i)*256 + c + 128];
#pragma unroll
      for (int j = 0; j < 36; j++){
        float t = t_lds[i][c0 + j];
        accK[j] += wk_ * t;
        accV[j] += wv_ * t;
      }
    }
  }
  float bk_ = bKV[c], bv_ = bKV[c + 128];

  // q for this thread's 4 n-points
  float q[4];
  { float bqc = bq[c]; q[0]=bqc; q[1]=bqc; q[2]=bqc; q[3]=bqc; }
#pragma unroll 4
  for (int i = 0; i < COx; i++){
    float w = wqT[i*COx + c];
#pragma unroll
    for (int nl = 0; nl < 4; nl++) q[nl] += w * xr[i][half*4 + nl];
  }

  // softmax over K=9, weighted sum with V
#pragma unroll
  for (int nl = 0; nl < 4; nl++){
    float sk[KW];
    float mx = -1e30f;
#pragma unroll
    for (int k = 0; k < KW; k++){
      float s_ = q[nl] * (accK[nl*KW + k] + bk_);
      sk[k] = s_;
      mx = fmaxf(mx, s_);
    }
    float den = 0.f, num = 0.f;
#pragma unroll
    for (int k = 0; k < KW; k++){
      float e = __expf(sk[k] - mx);
      den += e;
      num += e * (accV[nl*KW + k] + bv_);
    }
    out_local[((size_t)b*COx + c)*NPTS + n0 + half*4 + nl] = num / den;
  }
}

// ---------------- conv GEMM, I=256 (concat x_row|out_local), R=256 -> two outputs ----------------
__global__ __launch_bounds__(256) void k_conv2x(const float* __restrict__ in0, const float* __restrict__ in1,
    const float* __restrict__ WT, const float* __restrict__ bias,
    float* __restrict__ out0, float* __restrict__ out1)
{
  const int b  = blockIdx.y;
  const int n0 = blockIdx.x * 40;
  const int tid = threadIdx.x;
  __shared__ float tile[256][40];
  for (int idx = tid; idx < 256*40; idx += 256){
    int i = idx / 40; int cc = idx - i*40;
    const float* src = (i < 128) ? (in0 + ((size_t)b*128 + i)*NPTS)
                                 : (in1 + ((size_t)b*128 + (i-128))*NPTS);
    tile[i][cc] = src[n0 + cc];
  }
  __syncthreads();
  const int r = tid;
  float acc[40];
  float bb = bias[r];
#pragma unroll
  for (int j = 0; j < 40; j++) acc[j] = bb;
#pragma unroll 4
  for (int i = 0; i < 256; i++){
    float w = WT[i*256 + r];
#pragma unroll
    for (int j = 0; j < 40; j++) acc[j] += w * tile[i][j];
  }
  float* dst = (r < 128) ? (out0 + ((size_t)b*128 + r)*NPTS + n0)
                         : (out1 + ((size_t)b*128 + (r-128))*NPTS + n0);
#pragma unroll
  for (int j = 0; j < 40; j++) dst[j] = acc[j];
}

// ---------------- conv GEMM, I=128, R=128 ----------------
__global__ __launch_bounds__(256) void k_conv1x(const float* __restrict__ in,
    const float* __restrict__ WT, const float* __restrict__ bias, float* __restrict__ out)
{
  const int b  = blockIdx.y;
  const int n0 = blockIdx.x * 40;
  const int tid = threadIdx.x;
  __shared__ float tile[128][40];
  for (int idx = tid; idx < 128*40; idx += 256){
    int i = idx / 40; int cc = idx - i*40;
    tile[i][cc] = in[((size_t)b*128 + i)*NPTS + n0 + cc];
  }
  __syncthreads();
  const int r = tid & 127;
  const int j0 = (tid >> 7) * 20;
  float acc[20];
  float bb = bias[r];
#pragma unroll
  for (int j = 0; j < 20; j++) acc[j] = bb;
#pragma unroll 4
  for (int i = 0; i < 128; i++){
    float w = WT[i*128 + r];
#pragma unroll
    for (int j = 0; j < 20; j++) acc[j] += w * tile[i][j0 + j];
  }
  float* dst = out + ((size_t)b*128 + r)*NPTS + n0 + j0;
#pragma unroll
  for (int j = 0; j < 20; j++) dst[j] = acc[j];
}

// ---------------- per-(b,c) stats over N=2000 ----------------
__global__ __launch_bounds__(256) void k_cstats(const float* __restrict__ x,
    float* __restrict__ csum, float* __restrict__ csumsq){
  int bc = blockIdx.x;
  const float4* p = (const float4*)(x + (size_t)bc * NPTS);
  float s = 0.f, ss = 0.f;
  for (int idx = threadIdx.x; idx < NPTS/4; idx += 256){
    float4 v = p[idx];
    s  += v.x + v.y + v.z + v.w;
    ss += v.x*v.x + v.y*v.y + v.z*v.z + v.w*v.w;
  }
  __shared__ float rs[256], rss[256];
  rs[threadIdx.x] = s; rss[threadIdx.x] = ss;
  __syncthreads();
  for (int off = 128; off > 0; off >>= 1){
    if (threadIdx.x < off){ rs[threadIdx.x] += rs[threadIdx.x+off]; rss[threadIdx.x] += rss[threadIdx.x+off]; }
    __syncthreads();
  }
  if (threadIdx.x == 0){ csum[bc] = rs[0]; csumsq[bc] = rss[0]; }
}

__global__ void k_cscale(const float* __restrict__ csum, const float* __restrict__ csumsq,
                         float* __restrict__ cm, float* __restrict__ cs){
  int c = threadIdx.x;  // 0..127
  float vl[NB], ml[NB];
  float V = 0.f;
  for (int b = 0; b < NB; b++){
    int bc = b*COx + c;
    float m = csum[bc] * (1.f/(float)NPTS);
    float v = csumsq[bc] * (1.f/(float)NPTS) - m*m;
    ml[b] = m; vl[b] = v;
    V += v / (v + 1e-5f);
  }
  V *= (1.f/(float)NB);
  float bs = rsqrtf(V + 1e-5f);
  for (int b = 0; b < NB; b++){
    int bc = b*COx + c;
    cm[bc] = ml[b];
    cs[bc] = rsqrtf(vl[b] + 1e-5f) * bs;
  }
}

// out = relu((c - m)*s) + add1 [+ add2]
__global__ __launch_bounds__(256) void k_normadd(const float* __restrict__ cbuf,
    const float* __restrict__ add1, const float* __restrict__ add2,
    const float* __restrict__ cm, const float* __restrict__ cs, float* __restrict__ out){
  int bc = blockIdx.x;
  float m = cm[bc], s = cs[bc];
  const float4* pc = (const float4*)(cbuf + (size_t)bc*NPTS);
  const float4* p1 = (const float4*)(add1 + (size_t)bc*NPTS);
  const float4* p2 = add2 ? (const float4*)(add2 + (size_t)bc*NPTS) : nullptr;
  float4* po = (float4*)(out + (size_t)bc*NPTS);
  for (int idx = threadIdx.x; idx < NPTS/4; idx += 256){
    float4 v = pc[idx], a = p1[idx];
    float4 r;
    r.x = fmaxf((v.x - m)*s, 0.f) + a.x;
    r.y = fmaxf((v.y - m)*s, 0.f) + a.y;
    r.z = fmaxf((v.z - m)*s, 0.f) + a.z;
    r.w = fmaxf((v.w - m)*s, 0.f) + a.w;
    if (p2){ float4 a2 = p2[idx]; r.x += a2.x; r.y += a2.y; r.z += a2.z; r.w += a2.w; }
    po[idx] = r;
  }
}

// o3 = relu(norm(c3)+x1); t = x_row + g*o3; out = 0.5*(t + mean_c t)
__global__ __launch_bounds__(256) void k_final(const float* __restrict__ c3, const float* __restrict__ x1,
    const float* __restrict__ x_row, const float* __restrict__ cm, const float* __restrict__ cs,
    const float* __restrict__ gamma1, float* __restrict__ out)
{
  const int b  = blockIdx.y;
  const int n0 = blockIdx.x * 50;
  const int tid = threadIdx.x;
  const float g = gamma1[0];
  __shared__ float tt[128][50];
  __shared__ float part[4][50];
  for (int idx = tid; idx < 128*50; idx += 256){
    int c = idx / 50; int j = idx - c*50;
    size_t off = ((size_t)b*COx + c)*NPTS + n0 + j;
    float o3 = fmaxf((c3[off] - cm[b*COx + c]) * cs[b*COx + c] + x1[off], 0.f);
    tt[c][j] = x_row[off] + g * o3;
  }
  __syncthreads();
  if (tid < 200){
    int gg = tid / 50, j = tid - gg*50;
    float s = 0.f;
    for (int c = gg*32; c < gg*32 + 32; c++) s += tt[c][j];
    part[gg][j] = s;
  }
  __syncthreads();
  for (int idx = tid; idx < 128*50; idx += 256){
    int c = idx / 50; int j = idx - c*50;
    float mean = (part[0][j] + part[1][j] + part[2][j] + part[3][j]) * (1.f/128.f);
    out[((size_t)b*COx + c)*NPTS + n0 + j] = 0.5f * (tt[c][j] + mean);
  }
}

extern "C" void kernel_launch(void* const* d_in, const int* in_sizes, int n_in,
                              void* d_out, int out_size, void* d_ws, size_t ws_size,
                              hipStream_t stream){
  (void)in_sizes; (void)n_in; (void)out_size; (void)ws_size;
  const float* x_row   = (const float*)d_in[0];
  const float* x_local = (const float*)d_in[1];
  const float* w_att1  = (const float*)d_in[2];
  const float* b_att1  = (const float*)d_in[3];
  const float* wq      = (const float*)d_in[4];
  const float* bq      = (const float*)d_in[5];
  const float* wk      = (const float*)d_in[6];
  const float* bk      = (const float*)d_in[7];
  const float* wv      = (const float*)d_in[8];
  const float* bv      = (const float*)d_in[9];
  const float* w_right = (const float*)d_in[10];
  const float* b_right = (const float*)d_in[11];
  const float* w_l1    = (const float*)d_in[12];
  const float* b_l1    = (const float*)d_in[13];
  const float* w_l2    = (const float*)d_in[14];
  const float* b_l2    = (const float*)d_in[15];
  const float* w_l3    = (const float*)d_in[16];
  const float* b_l3    = (const float*)d_in[17];
  const float* gamma1  = (const float*)d_in[18];
  float* out = (float*)d_out;

  float* ws     = (float*)d_ws;
  float* sum    = ws;            // 4096
  float* sumsq  = ws + 4096;     // 4096
  float* mArr   = ws + 8192;     // 4096
  float* sArr   = ws + 12288;    // 4096
  float* WT_kv  = ws + 16384;    // 65536
  float* bKV    = ws + 81920;    // 256
  float* wqT    = ws + 82176;    // 16384
  float* WT2    = ws + 98560;    // 65536
  float* bias2  = ws + 164096;   // 256
  float* WT3    = ws + 164352;   // 16384
  float* WT4    = ws + 180736;   // 16384
  float* csum   = ws + 197120;   // 2048
  float* csumsq = ws + 199168;   // 2048
  float* cm     = ws + 201216;   // 2048
  float* cs     = ws + 203264;   // 2048
  float* P0 = ws + 262144;            // 4,096,000 each
  float* P1 = P0 + 4096000;
  float* P2 = P1 + 4096000;
  float* P3 = P2 + 4096000;

  // stats + weight prep
  k_xstats  <<<4096, 256, 0, stream>>>(x_local, sum, sumsq);
  k_xscale  <<<1, 256, 0, stream>>>(sum, sumsq, mArr, sArr);
  k_prep_kv <<<256, 256, 0, stream>>>(w_att1, wk, wv, b_att1, bk, bv, WT_kv, bKV);
  k_transpose<<<64, 256, 0, stream>>>(wq,   wqT, 128, 128);
  k_prep2   <<<256, 256, 0, stream>>>(w_right, w_l1, b_right, b_l1, WT2, bias2);
  k_transpose<<<64, 256, 0, stream>>>(w_l2, WT3, 128, 128);
  k_transpose<<<64, 256, 0, stream>>>(w_l3, WT4, 128, 128);

  // fused attention -> out_local (P0)
  k_attn<<<dim3(NPTS/8, NB), 256, 0, stream>>>(x_local, x_row, mArr, sArr, WT_kv, bKV, wqT, bq, P0);

  // x1 (P1), c1 (P2)
  k_conv2x<<<dim3(NPTS/40, NB), 256, 0, stream>>>(x_row, P0, WT2, bias2, P1, P2);
  k_cstats<<<NB*COx, 256, 0, stream>>>(P2, csum, csumsq);
  k_cscale<<<1, 128, 0, stream>>>(csum, csumsq, cm, cs);
  // o1 (P3) = relu(norm(c1)) + x1
  k_normadd<<<NB*COx, 256, 0, stream>>>(P2, P1, nullptr, cm, cs, P3);

  // c2 (P0) = w_l2 . o1
  k_conv1x<<<dim3(NPTS/40, NB), 256, 0, stream>>>(P3, WT3, b_l2, P0);
  k_cstats<<<NB*COx, 256, 0, stream>>>(P0, csum, csumsq);
  k_cscale<<<1, 128, 0, stream>>>(csum, csumsq, cm, cs);
  // o2 (P2) = relu(norm(c2)) + o1 + x1
  k_normadd<<<NB*COx, 256, 0, stream>>>(P0, P3, P1, cm, cs, P2);

  // c3 (P3) = w_l3 . o2
  k_conv1x<<<dim3(NPTS/40, NB), 256, 0, stream>>>(P2, WT4, b_l3, P3);
  k_cstats<<<NB*COx, 256, 0, stream>>>(P3, csum, csumsq);
  k_cscale<<<1, 128, 0, stream>>>(csum, csumsq, cm, cs);

  // final: o3 = relu(norm(c3)+x1); out = 0.5*((x_row + g*o3) + mean_c(...))
  k_final<<<dim3(NPTS/50, NB), 256, 0, stream>>>(P3, P1, x_row, cm, cs, gamma1, out);
}

// Round 2
// 575.560 us; speedup vs baseline: 2.0005x; 2.0005x over previous
//
#include <hip/hip_runtime.h>
#include <math.h>

#define NB    16
#define CIx   256
#define COx   128
#define NPTS  2000
#define KW    9
#define NKx   18000   // NPTS*KW

typedef short bf16x8 __attribute__((ext_vector_type(8)));
typedef float f32x4  __attribute__((ext_vector_type(4)));

__device__ __forceinline__ ushort f2bf(float f){
  unsigned u = __builtin_bit_cast(unsigned, f);
  u = (u + 0x7fffu + ((u>>16)&1u)) >> 16;
  return (ushort)u;
}
__device__ __forceinline__ float bf2f(ushort h){
  unsigned u = ((unsigned)h)<<16;
  return __builtin_bit_cast(float, u);
}

// ---------------- stats over x_local: per (b,i) sum/sumsq over 18000 ----------------
__global__ __launch_bounds__(256) void k_xstats(const float* __restrict__ xl,
    float* __restrict__ sum, float* __restrict__ sumsq){
  int bi = blockIdx.x;                       // b*256 + i
  const float4* p = (const float4*)(xl + (size_t)bi * NKx);
  float s = 0.f, ss = 0.f;
  for (int idx = threadIdx.x; idx < NKx/4; idx += 256){
    float4 v = p[idx];
    s  += v.x + v.y + v.z + v.w;
    ss += v.x*v.x + v.y*v.y + v.z*v.z + v.w*v.w;
  }
  __shared__ float rs[256], rss[256];
  rs[threadIdx.x] = s; rss[threadIdx.x] = ss;
  __syncthreads();
  for (int off = 128; off > 0; off >>= 1){
    if (threadIdx.x < off){ rs[threadIdx.x] += rs[threadIdx.x+off]; rss[threadIdx.x] += rss[threadIdx.x+off]; }
    __syncthreads();
  }
  if (threadIdx.x == 0){ sum[bi] = rs[0]; sumsq[bi] = rss[0]; }
}

// inorm(1e-3) + bnorm(1e-5) collapse: per (b,i) m and combined scale s
__global__ void k_xscale(const float* __restrict__ sum, const float* __restrict__ sumsq,
                         float* __restrict__ mOut, float* __restrict__ sOut){
  int i = threadIdx.x;                       // channel 0..255
  float vl[NB], ml[NB];
  float V = 0.f;
  for (int b = 0; b < NB; b++){
    int bi = b*CIx + i;
    float m = sum[bi] * (1.f/(float)NKx);
    float v = sumsq[bi] * (1.f/(float)NKx) - m*m;
    ml[b] = m; vl[b] = v;
    V += v / (v + 1e-3f);
  }
  V *= (1.f/(float)NB);
  float bs = rsqrtf(V + 1e-5f);
  for (int b = 0; b < NB; b++){
    int bi = b*CIx + i;
    mOut[bi] = ml[b];
    sOut[bi] = rsqrtf(vl[b] + 1e-3f) * bs;
  }
}

// ---- fold wk@w_att1 / wv@w_att1 into Wf[r][i] bf16 (r<128:K, r>=128:V), row-major ----
__global__ void k_prep_kv(const float* __restrict__ w_att1, const float* __restrict__ wk,
                          const float* __restrict__ wv, const float* __restrict__ b_att1,
                          const float* __restrict__ bk, const float* __restrict__ bv,
                          ushort* __restrict__ Wf, float* __restrict__ bKV){
  int r = blockIdx.x;   // 0..255
  int i = threadIdx.x;  // 0..255
  const float* wr = (r < 128) ? (wk + r*128) : (wv + (r-128)*128);
  float acc = 0.f;
  for (int c = 0; c < 128; c++) acc += wr[c] * w_att1[c*CIx + i];
  Wf[r*256 + i] = f2bf(acc);
  if (i == 0){
    float bacc = (r < 128) ? bk[r] : bv[r-128];
    for (int c = 0; c < 128; c++) bacc += wr[c] * b_att1[c];
    bKV[r] = bacc;
  }
}

// generic transpose: out[i*R + r] = in[r*I + i]
__global__ void k_transpose(const float* __restrict__ in, float* __restrict__ out, int R, int I){
  int idx = blockIdx.x*256 + threadIdx.x;
  if (idx < R*I){ int r = idx / I; int i = idx - r*I; out[i*R + r] = in[idx]; }
}

// pack [w_right; w_l1] transposed: WT2[i][r]
__global__ void k_prep2(const float* __restrict__ w_right, const float* __restrict__ w_l1,
                        const float* __restrict__ b_right, const float* __restrict__ b_l1,
                        float* __restrict__ WT2, float* __restrict__ bias2){
  int r = blockIdx.x; int i = threadIdx.x;
  const float* w = (r < 128) ? (w_right + r*CIx) : (w_l1 + (r-128)*CIx);
  WT2[i*256 + r] = w[i];
  if (i == 0) bias2[r] = (r < 128) ? b_right[r] : b_l1[r-128];
}

// ---------------- fused MFMA attention ----------------
// D[colx][r] = sum_i xnorm[i][col0+colx] * Wf[r][i]   (C^T orientation)
// A-frag (arg0) = x from LDS frag-linear; B-frag (arg1) = Wf from global (L2-resident).
// wave w owns channel groups ct = {w, w+4} (K) and {w+8, w+12} (V) -> lane holds matched K/V.
__global__ __launch_bounds__(256,2) void k_attn_mfma(
    const float* __restrict__ xl, const float* __restrict__ x_row,
    const float* __restrict__ mArr, const float* __restrict__ sArr,
    const ushort* __restrict__ Wf, const float* __restrict__ bKV,
    const float* __restrict__ wqT, const float* __restrict__ bq,
    float* __restrict__ out_local)
{
  const int b   = blockIdx.y;
  const int n0  = blockIdx.x * 16;
  const int col0 = n0 * KW;                 // 144 * blockIdx.x
  const int tid = threadIdx.x;
  const int w   = tid >> 6;
  const int lane = tid & 63;
  const int c16 = lane & 15, g = lane >> 4;

  __shared__ ushort blds[2][4608];          // frag-linear: slot=((col>>4)*4+kg)*16+(col&15), 8 i/slot
  __shared__ ushort elds[4][4][16][82];     // [wave][ctj][c16][col window 80 (+2 pad)]

  f32x4 acc[9][4];
#pragma unroll
  for (int mt = 0; mt < 9; mt++)
#pragma unroll
    for (int j = 0; j < 4; j++) acc[mt][j] = (f32x4)0.f;

  const size_t xbase = (size_t)b * CIx * NKx + col0;

  auto STAGE = [&](int s, int buf){
    unsigned* bl = (unsigned*)&blds[buf][0];
#pragma unroll
    for (int qq = 0; qq < 9; qq++){
      int idx = tid + 256*qq;               // 0..2303
      int ip  = idx / 144;                  // i-pair 0..15
      int col = idx - ip*144;               // 0..143
      int i   = s*32 + 2*ip;
      const float* gp = xl + xbase + (size_t)i * NKx + col;
      float f0 = gp[0], f1 = gp[NKx];
      float m0 = mArr[b*CIx + i],     s0 = sArr[b*CIx + i];
      float m1 = mArr[b*CIx + i + 1], s1 = sArr[b*CIx + i + 1];
      float v0 = fmaxf((f0 - m0)*s0, 0.f);
      float v1 = fmaxf((f1 - m1)*s1, 0.f);
      unsigned pk = (unsigned)f2bf(v0) | ((unsigned)f2bf(v1) << 16);
      int slot = ((col >> 4)*4 + (ip >> 2))*16 + (col & 15);
      bl[slot*4 + (ip & 3)] = pk;
    }
  };

  STAGE(0, 0);
  __syncthreads();

  const int ct0 = w, ct1 = w + 4, ct2 = w + 8, ct3 = w + 12;

  for (int s = 0; s < 8; s++){
    int cur = s & 1;
    bf16x8 wf0 = *(const bf16x8*)(Wf + (ct0*16 + c16)*256 + s*32 + g*8);
    bf16x8 wf1 = *(const bf16x8*)(Wf + (ct1*16 + c16)*256 + s*32 + g*8);
    bf16x8 wf2 = *(const bf16x8*)(Wf + (ct2*16 + c16)*256 + s*32 + g*8);
    bf16x8 wf3 = *(const bf16x8*)(Wf + (ct3*16 + c16)*256 + s*32 + g*8);
    if (s < 7) STAGE(s+1, cur ^ 1);
#pragma unroll
    for (int mt = 0; mt < 9; mt++){
      int slot = (mt*4 + g)*16 + c16;
      bf16x8 af = *(const bf16x8*)&blds[cur][slot*8];
      acc[mt][0] = __builtin_amdgcn_mfma_f32_16x16x32_bf16(af, wf0, acc[mt][0], 0,0,0);
      acc[mt][1] = __builtin_amdgcn_mfma_f32_16x16x32_bf16(af, wf1, acc[mt][1], 0,0,0);
      acc[mt][2] = __builtin_amdgcn_mfma_f32_16x16x32_bf16(af, wf2, acc[mt][2], 0,0,0);
      acc[mt][3] = __builtin_amdgcn_mfma_f32_16x16x32_bf16(af, wf3, acc[mt][3], 0,0,0);
    }
    __syncthreads();
  }

  // ---- q precompute: channels ch0 = 16w+c16, ch1 = ch0+64; n slots {2g,2g+1,8+2g,8+2g+1} ----
  float qv[2][4];
  {
    int ch0 = w*16 + c16, ch1 = ch0 + 64;
    float b0 = bq[ch0], b1 = bq[ch1];
    qv[0][0]=b0; qv[0][1]=b0; qv[0][2]=b0; qv[0][3]=b0;
    qv[1][0]=b1; qv[1][1]=b1; qv[1][2]=b1; qv[1][3]=b1;
    const float* xr = x_row + (size_t)b * COx * NPTS + n0;
    for (int i = 0; i < COx; i++){
      float w0 = wqT[i*COx + ch0];
      float w1 = wqT[i*COx + ch1];
      float2 xa = *(const float2*)(xr + (size_t)i*NPTS + 2*g);
      float2 xb = *(const float2*)(xr + (size_t)i*NPTS + 8 + 2*g);
      qv[0][0] += w0*xa.x; qv[0][1] += w0*xa.y; qv[0][2] += w0*xb.x; qv[0][3] += w0*xb.y;
      qv[1][0] += w1*xa.x; qv[1][1] += w1*xa.y; qv[1][2] += w1*xb.x; qv[1][3] += w1*xb.y;
    }
  }
  const int chA = w*16 + c16;
  float bkv0 = bKV[chA], bkv1 = bKV[chA + 64];
  float bvv0 = bKV[128 + chA], bvv1 = bKV[128 + chA + 64];

  // ---- 2-phase epilogue: dump acc -> elds (bf16), softmax over K=9, PV, store ----
#pragma unroll
  for (int p = 0; p < 2; p++){
#pragma unroll
    for (int mtl = 0; mtl < 5; mtl++){
      int mt = 4*p + mtl;
      int colb = 16*mt + 4*g - 64*p;        // window offset for reg 0
#pragma unroll
      for (int j = 0; j < 4; j++){
#pragma unroll
        for (int r2 = 0; r2 < 2; r2++){
          unsigned pk = (unsigned)f2bf(acc[mt][j][2*r2]) | ((unsigned)f2bf(acc[mt][j][2*r2+1]) << 16);
          *(unsigned*)&elds[w][j][c16][colb + 2*r2] = pk;
        }
      }
    }
    __syncthreads();

#pragma unroll
    for (int h = 0; h < 2; h++){
      float bk_ = h ? bkv1 : bkv0;
      float bv_ = h ? bvv1 : bvv0;
      float o2[2];
#pragma unroll
      for (int t = 0; t < 2; t++){
        int nloc = 8*p + 2*g + t;
        int cbase = nloc*KW - 64*p;
        float qq = qv[h][2*p + t];
        float sc[KW];
        float mx = -1e30f;
#pragma unroll
        for (int k = 0; k < KW; k++){
          float kf = bf2f(elds[w][h][c16][cbase + k]) + bk_;
          float s_ = qq * kf;
          sc[k] = s_;
          mx = fmaxf(mx, s_);
        }
        float den = 0.f, num = 0.f;
#pragma unroll
        for (int k = 0; k < KW; k++){
          float e = __expf(sc[k] - mx);
          den += e;
          num += e * (bf2f(elds[w][2+h][c16][cbase + k]) + bv_);
        }
        o2[t] = num / den;
      }
      int ch = chA + 64*h;
      *(float2*)&out_local[((size_t)(b*COx + ch))*NPTS + n0 + 8*p + 2*g] = make_float2(o2[0], o2[1]);
    }
    __syncthreads();
  }
}

// ---------------- conv GEMM, I=256 (concat x_row|out_local), R=256 -> two outputs ----------------
__global__ __launch_bounds__(256) void k_conv2x(const float* __restrict__ in0, const float* __restrict__ in1,
    const float* __restrict__ WT, const float* __restrict__ bias,
    float* __restrict__ out0, float* __restrict__ out1)
{
  const int b  = blockIdx.y;
  const int n0 = blockIdx.x * 40;
  const int tid = threadIdx.x;
  __shared__ float tile[256][40];
  for (int idx = tid; idx < 256*40; idx += 256){
    int i = idx / 40; int cc = idx - i*40;
    const float* src = (i < 128) ? (in0 + ((size_t)b*128 + i)*NPTS)
                                 : (in1 + ((size_t)b*128 + (i-128))*NPTS);
    tile[i][cc] = src[n0 + cc];
  }
  __syncthreads();
  const int r = tid;
  float acc[40];
  float bb = bias[r];
#pragma unroll
  for (int j = 0; j < 40; j++) acc[j] = bb;
#pragma unroll 4
  for (int i = 0; i < 256; i++){
    float w = WT[i*256 + r];
#pragma unroll
    for (int j = 0; j < 40; j++) acc[j] += w * tile[i][j];
  }
  float* dst = (r < 128) ? (out0 + ((size_t)b*128 + r)*NPTS + n0)
                         : (out1 + ((size_t)b*128 + (r-128))*NPTS + n0);
#pragma unroll
  for (int j = 0; j < 40; j++) dst[j] = acc[j];
}

// ---------------- conv GEMM, I=128, R=128 ----------------
__global__ __launch_bounds__(256) void k_conv1x(const float* __restrict__ in,
    const float* __restrict__ WT, const float* __restrict__ bias, float* __restrict__ out)
{
  const int b  = blockIdx.y;
  const int n0 = blockIdx.x * 40;
  const int tid = threadIdx.x;
  __shared__ float tile[128][40];
  for (int idx = tid; idx < 128*40; idx += 256){
    int i = idx / 40; int cc = idx - i*40;
    tile[i][cc] = in[((size_t)b*128 + i)*NPTS + n0 + cc];
  }
  __syncthreads();
  const int r = tid & 127;
  const int j0 = (tid >> 7) * 20;
  float acc[20];
  float bb = bias[r];
#pragma unroll
  for (int j = 0; j < 20; j++) acc[j] = bb;
#pragma unroll 4
  for (int i = 0; i < 128; i++){
    float w = WT[i*128 + r];
#pragma unroll
    for (int j = 0; j < 20; j++) acc[j] += w * tile[i][j0 + j];
  }
  float* dst = out + ((size_t)b*128 + r)*NPTS + n0 + j0;
#pragma unroll
  for (int j = 0; j < 20; j++) dst[j] = acc[j];
}

// ---------------- per-(b,c) stats over N=2000 ----------------
__global__ __launch_bounds__(256) void k_cstats(const float* __restrict__ x,
    float* __restrict__ csum, float* __restrict__ csumsq){
  int bc = blockIdx.x;
  const float4* p = (const float4*)(x + (size_t)bc * NPTS);
  float s = 0.f, ss = 0.f;
  for (int idx = threadIdx.x; idx < NPTS/4; idx += 256){
    float4 v = p[idx];
    s  += v.x + v.y + v.z + v.w;
    ss += v.x*v.x + v.y*v.y + v.z*v.z + v.w*v.w;
  }
  __shared__ float rs[256], rss[256];
  rs[threadIdx.x] = s; rss[threadIdx.x] = ss;
  __syncthreads();
  for (int off = 128; off > 0; off >>= 1){
    if (threadIdx.x < off){ rs[threadIdx.x] += rs[threadIdx.x+off]; rss[threadIdx.x] += rss[threadIdx.x+off]; }
    __syncthreads();
  }
  if (threadIdx.x == 0){ csum[bc] = rs[0]; csumsq[bc] = rss[0]; }
}

__global__ void k_cscale(const float* __restrict__ csum, const float* __restrict__ csumsq,
                         float* __restrict__ cm, float* __restrict__ cs){
  int c = threadIdx.x;  // 0..127
  float vl[NB], ml[NB];
  float V = 0.f;
  for (int b = 0; b < NB; b++){
    int bc = b*COx + c;
    float m = csum[bc] * (1.f/(float)NPTS);
    float v = csumsq[bc] * (1.f/(float)NPTS) - m*m;
    ml[b] = m; vl[b] = v;
    V += v / (v + 1e-5f);
  }
  V *= (1.f/(float)NB);
  float bs = rsqrtf(V + 1e-5f);
  for (int b = 0; b < NB; b++){
    int bc = b*COx + c;
    cm[bc] = ml[b];
    cs[bc] = rsqrtf(vl[b] + 1e-5f) * bs;
  }
}

// out = relu((c - m)*s) + add1 [+ add2]
__global__ __launch_bounds__(256) void k_normadd(const float* __restrict__ cbuf,
    const float* __restrict__ add1, const float* __restrict__ add2,
    const float* __restrict__ cm, const float* __restrict__ cs, float* __restrict__ out){
  int bc = blockIdx.x;
  float m = cm[bc], s = cs[bc];
  const float4* pc = (const float4*)(cbuf + (size_t)bc*NPTS);
  const float4* p1 = (const float4*)(add1 + (size_t)bc*NPTS);
  const float4* p2 = add2 ? (const float4*)(add2 + (size_t)bc*NPTS) : nullptr;
  float4* po = (float4*)(out + (size_t)bc*NPTS);
  for (int idx = threadIdx.x; idx < NPTS/4; idx += 256){
    float4 v = pc[idx], a = p1[idx];
    float4 r;
    r.x = fmaxf((v.x - m)*s, 0.f) + a.x;
    r.y = fmaxf((v.y - m)*s, 0.f) + a.y;
    r.z = fmaxf((v.z - m)*s, 0.f) + a.z;
    r.w = fmaxf((v.w - m)*s, 0.f) + a.w;
    if (p2){ float4 a2 = p2[idx]; r.x += a2.x; r.y += a2.y; r.z += a2.z; r.w += a2.w; }
    po[idx] = r;
  }
}

// o3 = relu(norm(c3)+x1); t = x_row + g*o3; out = 0.5*(t + mean_c t)
__global__ __launch_bounds__(256) void k_final(const float* __restrict__ c3, const float* __restrict__ x1,
    const float* __restrict__ x_row, const float* __restrict__ cm, const float* __restrict__ cs,
    const float* __restrict__ gamma1, float* __restrict__ out)
{
  const int b  = blockIdx.y;
  const int n0 = blockIdx.x * 50;
  const int tid = threadIdx.x;
  const float g = gamma1[0];
  __shared__ float tt[128][50];
  __shared__ float part[4][50];
  for (int idx = tid; idx < 128*50; idx += 256){
    int c = idx / 50; int j = idx - c*50;
    size_t off = ((size_t)b*COx + c)*NPTS + n0 + j;
    float o3 = fmaxf((c3[off] - cm[b*COx + c]) * cs[b*COx + c] + x1[off], 0.f);
    tt[c][j] = x_row[off] + g * o3;
  }
  __syncthreads();
  if (tid < 200){
    int gg = tid / 50, j = tid - gg*50;
    float s = 0.f;
    for (int c = gg*32; c < gg*32 + 32; c++) s += tt[c][j];
    part[gg][j] = s;
  }
  __syncthreads();
  for (int idx = tid; idx < 128*50; idx += 256){
    int c = idx / 50; int j = idx - c*50;
    float mean = (part[0][j] + part[1][j] + part[2][j] + part[3][j]) * (1.f/128.f);
    out[((size_t)b*COx + c)*NPTS + n0 + j] = 0.5f * (tt[c][j] + mean);
  }
}

extern "C" void kernel_launch(void* const* d_in, const int* in_sizes, int n_in,
                              void* d_out, int out_size, void* d_ws, size_t ws_size,
                              hipStream_t stream){
  (void)in_sizes; (void)n_in; (void)out_size; (void)ws_size;
  const float* x_row   = (const float*)d_in[0];
  const float* x_local = (const float*)d_in[1];
  const float* w_att1  = (const float*)d_in[2];
  const float* b_att1  = (const float*)d_in[3];
  const float* wq      = (const float*)d_in[4];
  const float* bq      = (const float*)d_in[5];
  const float* wk      = (const float*)d_in[6];
  const float* bk      = (const float*)d_in[7];
  const float* wv      = (const float*)d_in[8];
  const float* bv      = (const float*)d_in[9];
  const float* w_right = (const float*)d_in[10];
  const float* b_right = (const float*)d_in[11];
  const float* w_l1    = (const float*)d_in[12];
  const float* b_l1    = (const float*)d_in[13];
  const float* w_l2    = (const float*)d_in[14];
  const float* b_l2    = (const float*)d_in[15];
  const float* w_l3    = (const float*)d_in[16];
  const float* b_l3    = (const float*)d_in[17];
  const float* gamma1  = (const float*)d_in[18];
  float* out = (float*)d_out;

  float*  ws     = (float*)d_ws;
  float*  sum    = ws;              // 4096
  float*  sumsq  = ws + 4096;       // 4096
  float*  mArr   = ws + 8192;       // 4096
  float*  sArr   = ws + 12288;      // 4096
  ushort* Wf     = (ushort*)(ws + 16384);  // 65536 ushort = 32768 floats
  float*  bKV    = ws + 49152;      // 256
  float*  wqT    = ws + 49408;      // 16384
  float*  WT2    = ws + 65792;      // 65536
  float*  bias2  = ws + 131328;     // 256
  float*  WT3    = ws + 131584;     // 16384
  float*  WT4    = ws + 147968;     // 16384
  float*  csum   = ws + 164352;     // 2048
  float*  csumsq = ws + 166400;     // 2048
  float*  cm     = ws + 168448;     // 2048
  float*  cs     = ws + 170496;     // 2048
  float*  P0 = ws + 262144;         // 4,096,000 each
  float*  P1 = P0 + 4096000;
  float*  P2 = P1 + 4096000;
  float*  P3 = P2 + 4096000;

  // stats + weight prep
  k_xstats  <<<4096, 256, 0, stream>>>(x_local, sum, sumsq);
  k_xscale  <<<1, 256, 0, stream>>>(sum, sumsq, mArr, sArr);
  k_prep_kv <<<256, 256, 0, stream>>>(w_att1, wk, wv, b_att1, bk, bv, Wf, bKV);
  k_transpose<<<64, 256, 0, stream>>>(wq,   wqT, 128, 128);
  k_prep2   <<<256, 256, 0, stream>>>(w_right, w_l1, b_right, b_l1, WT2, bias2);
  k_transpose<<<64, 256, 0, stream>>>(w_l2, WT3, 128, 128);
  k_transpose<<<64, 256, 0, stream>>>(w_l3, WT4, 128, 128);

  // fused MFMA attention -> out_local (P0)
  k_attn_mfma<<<dim3(125, NB), 256, 0, stream>>>(x_local, x_row, mArr, sArr, Wf, bKV, wqT, bq, P0);

  // x1 (P1), c1 (P2)
  k_conv2x<<<dim3(NPTS/40, NB), 256, 0, stream>>>(x_row, P0, WT2, bias2, P1, P2);
  k_cstats<<<NB*COx, 256, 0, stream>>>(P2, csum, csumsq);
  k_cscale<<<1, 128, 0, stream>>>(csum, csumsq, cm, cs);
  // o1 (P3) = relu(norm(c1)) + x1
  k_normadd<<<NB*COx, 256, 0, stream>>>(P2, P1, nullptr, cm, cs, P3);

  // c2 (P0) = w_l2 . o1
  k_conv1x<<<dim3(NPTS/40, NB), 256, 0, stream>>>(P3, WT3, b_l2, P0);
  k_cstats<<<NB*COx, 256, 0, stream>>>(P0, csum, csumsq);
  k_cscale<<<1, 128, 0, stream>>>(csum, csumsq, cm, cs);
  // o2 (P2) = relu(norm(c2)) + o1 + x1
  k_normadd<<<NB*COx, 256, 0, stream>>>(P0, P3, P1, cm, cs, P2);

  // c3 (P3) = w_l3 . o2
  k_conv1x<<<dim3(NPTS/40, NB), 256, 0, stream>>>(P2, WT4, b_l3, P3);
  k_cstats<<<NB*COx, 256, 0, stream>>>(P3, csum, csumsq);
  k_cscale<<<1, 128, 0, stream>>>(csum, csumsq, cm, cs);

  // final: o3 = relu(norm(c3)+x1); out = 0.5*((x_row + g*o3) + mean_c(...))
  k_final<<<dim3(NPTS/50, NB), 256, 0, stream>>>(P3, P1, x_row, cm, cs, gamma1, out);
}

// Round 3
// 533.019 us; speedup vs baseline: 2.1601x; 1.0798x over previous
//
#include <hip/hip_runtime.h>
#include <math.h>

#define NB    16
#define CIx   256
#define COx   128
#define NPTS  2000
#define KW    9
#define NKx   18000   // NPTS*KW

typedef short bf16x8 __attribute__((ext_vector_type(8)));
typedef float f32x4  __attribute__((ext_vector_type(4)));

__device__ __forceinline__ ushort f2bf(float f){
  unsigned u = __builtin_bit_cast(unsigned, f);
  u = (u + 0x7fffu + ((u>>16)&1u)) >> 16;
  return (ushort)u;
}
__device__ __forceinline__ float bf2f(ushort h){
  unsigned u = ((unsigned)h)<<16;
  return __builtin_bit_cast(float, u);
}

// ---------------- stats over x_local: per (b,i) sum/sumsq over 18000 ----------------
__global__ __launch_bounds__(256) void k_xstats(const float* __restrict__ xl,
    float* __restrict__ sum, float* __restrict__ sumsq){
  int bi = blockIdx.x;                       // b*256 + i
  const float4* p = (const float4*)(xl + (size_t)bi * NKx);
  float s = 0.f, ss = 0.f;
  for (int idx = threadIdx.x; idx < NKx/4; idx += 256){
    float4 v = p[idx];
    s  += v.x + v.y + v.z + v.w;
    ss += v.x*v.x + v.y*v.y + v.z*v.z + v.w*v.w;
  }
  __shared__ float rs[256], rss[256];
  rs[threadIdx.x] = s; rss[threadIdx.x] = ss;
  __syncthreads();
  for (int off = 128; off > 0; off >>= 1){
    if (threadIdx.x < off){ rs[threadIdx.x] += rs[threadIdx.x+off]; rss[threadIdx.x] += rss[threadIdx.x+off]; }
    __syncthreads();
  }
  if (threadIdx.x == 0){ sum[bi] = rs[0]; sumsq[bi] = rss[0]; }
}

// inorm(1e-3) + bnorm(1e-5) collapse: per (b,i) m and combined scale s
__global__ void k_xscale(const float* __restrict__ sum, const float* __restrict__ sumsq,
                         float* __restrict__ mOut, float* __restrict__ sOut){
  int i = threadIdx.x;                       // channel 0..255
  float vl[NB], ml[NB];
  float V = 0.f;
  for (int b = 0; b < NB; b++){
    int bi = b*CIx + i;
    float m = sum[bi] * (1.f/(float)NKx);
    float v = sumsq[bi] * (1.f/(float)NKx) - m*m;
    ml[b] = m; vl[b] = v;
    V += v / (v + 1e-3f);
  }
  V *= (1.f/(float)NB);
  float bs = rsqrtf(V + 1e-5f);
  for (int b = 0; b < NB; b++){
    int bi = b*CIx + i;
    mOut[bi] = ml[b];
    sOut[bi] = rsqrtf(vl[b] + 1e-3f) * bs;
  }
}

// ---- fold wk@w_att1 / wv@w_att1 into Wf[r][i] bf16 (r<128:K, r>=128:V), row-major ----
__global__ void k_prep_kv(const float* __restrict__ w_att1, const float* __restrict__ wk,
                          const float* __restrict__ wv, const float* __restrict__ b_att1,
                          const float* __restrict__ bk, const float* __restrict__ bv,
                          ushort* __restrict__ Wf, float* __restrict__ bKV){
  int r = blockIdx.x;   // 0..255
  int i = threadIdx.x;  // 0..255
  const float* wr = (r < 128) ? (wk + r*128) : (wv + (r-128)*128);
  float acc = 0.f;
  for (int c = 0; c < 128; c++) acc += wr[c] * w_att1[c*CIx + i];
  Wf[r*256 + i] = f2bf(acc);
  if (i == 0){
    float bacc = (r < 128) ? bk[r] : bv[r-128];
    for (int c = 0; c < 128; c++) bacc += wr[c] * b_att1[c];
    bKV[r] = bacc;
  }
}

// generic transpose: out[i*R + r] = in[r*I + i]
__global__ void k_transpose(const float* __restrict__ in, float* __restrict__ out, int R, int I){
  int idx = blockIdx.x*256 + threadIdx.x;
  if (idx < R*I){ int r = idx / I; int i = idx - r*I; out[i*R + r] = in[idx]; }
}

// pack [w_right; w_l1] transposed: WT2[i][r]
__global__ void k_prep2(const float* __restrict__ w_right, const float* __restrict__ w_l1,
                        const float* __restrict__ b_right, const float* __restrict__ b_l1,
                        float* __restrict__ WT2, float* __restrict__ bias2){
  int r = blockIdx.x; int i = threadIdx.x;
  const float* w = (r < 128) ? (w_right + r*CIx) : (w_l1 + (r-128)*CIx);
  WT2[i*256 + r] = w[i];
  if (i == 0) bias2[r] = (r < 128) ? b_right[r] : b_l1[r-128];
}

// ---------------- fused MFMA attention ----------------
// D[colx][r] = sum_i xnorm[i][col0+colx] * Wf[r][i]   (C^T orientation)
// Whole 144x256 window staged once (2 halves of 128 i), 288 MFMAs barrier-free.
// wlds layout: addr_ushort = ((s'*9+mt)*4+g)*128 + sigma(c16)*8 + io,
//   sigma(c16) = ((c16&3)<<2)|(c16>>2)  (bank rotate), io = i&7, s'=(i&127)>>5, g=(i>>3)&3.
// Epilogue LDS aliases wlds (wlds dead after main loop).
__global__ __launch_bounds__(256,2) void k_attn_mfma(
    const float* __restrict__ xl,
    const float* __restrict__ mArr, const float* __restrict__ sArr,
    const ushort* __restrict__ Wf, const float* __restrict__ bKV,
    const float* __restrict__ Pq,
    float* __restrict__ out_local)
{
  const int b   = blockIdx.y;
  const int n0  = blockIdx.x * 16;
  const int col0 = n0 * KW;                 // 144 * blockIdx.x
  const int tid = threadIdx.x;
  const int w   = tid >> 6;
  const int lane = tid & 63;
  const int c16 = lane & 15, g = lane >> 4;

  __shared__ ushort smem_u[20992];          // 41,984 B: wlds (18,432 us) then aliased as elds
  ushort* wlds = smem_u;
  ushort (*elds)[4][16][82] = (ushort (*)[4][16][82])smem_u;

  f32x4 acc[9][4];
#pragma unroll
  for (int mt = 0; mt < 9; mt++)
#pragma unroll
    for (int j = 0; j < 4; j++) acc[mt][j] = (f32x4)0.f;

  const int ct0 = w, ct1 = w + 4, ct2 = w + 8, ct3 = w + 12;
  const int sg_l = ((c16 & 3) << 2) | (c16 >> 2);

  for (int half = 0; half < 2; half++){
    __syncthreads();
    // ---- stage 128 i x 144 col: float4 reads, normalize+relu, bf16 pack, rotated LDS ----
    {
      const size_t xb = (size_t)b*CIx*NKx + (size_t)(half*128)*NKx + col0;
      const float* mB = mArr + b*CIx + half*128;
      const float* sB = sArr + b*CIx + half*128;
#pragma unroll
      for (int kk = 0; kk < 9; kk++){
        int flat = tid + 256*kk;            // 0..2303
        int il   = flat / 36;               // i-pair 0..63
        int c4   = flat - il*36;            // float4 col group 0..35
        int i_l  = il*2;
        int col  = c4*4;
        const float* gp = xl + xb + (size_t)i_l*NKx + col;
        float4 r0 = *(const float4*)gp;
        float4 r1 = *(const float4*)(gp + NKx);
        float m0 = mB[i_l],   s0 = sB[i_l];
        float m1 = mB[i_l+1], s1 = sB[i_l+1];
        int sp  = i_l >> 5;
        int g_  = (i_l >> 3) & 3;
        int io2 = il & 3;                   // u32 index within slot
        int mt  = col >> 4;
        unsigned* dstb = (unsigned*)wlds + ((sp*9 + mt)*4 + g_)*64 + io2;
        float a0[4] = {r0.x, r0.y, r0.z, r0.w};
        float a1[4] = {r1.x, r1.y, r1.z, r1.w};
#pragma unroll
        for (int j = 0; j < 4; j++){
          int cj = (col + j) & 15;
          int sg = ((cj & 3) << 2) | (cj >> 2);
          float v0 = fmaxf((a0[j] - m0)*s0, 0.f);
          float v1 = fmaxf((a1[j] - m1)*s1, 0.f);
          dstb[sg*4] = (unsigned)f2bf(v0) | ((unsigned)f2bf(v1) << 16);
        }
      }
    }
    __syncthreads();
    // ---- 4 K-steps, no barriers ----
#pragma unroll
    for (int sp = 0; sp < 4; sp++){
      int s = half*4 + sp;
      bf16x8 wf0 = *(const bf16x8*)(Wf + (ct0*16 + c16)*256 + s*32 + g*8);
      bf16x8 wf1 = *(const bf16x8*)(Wf + (ct1*16 + c16)*256 + s*32 + g*8);
      bf16x8 wf2 = *(const bf16x8*)(Wf + (ct2*16 + c16)*256 + s*32 + g*8);
      bf16x8 wf3 = *(const bf16x8*)(Wf + (ct3*16 + c16)*256 + s*32 + g*8);
#pragma unroll
      for (int mt = 0; mt < 9; mt++){
        bf16x8 af = *(const bf16x8*)(wlds + ((sp*9 + mt)*4 + g)*128 + sg_l*8);
        acc[mt][0] = __builtin_amdgcn_mfma_f32_16x16x32_bf16(af, wf0, acc[mt][0], 0,0,0);
        acc[mt][1] = __builtin_amdgcn_mfma_f32_16x16x32_bf16(af, wf1, acc[mt][1], 0,0,0);
        acc[mt][2] = __builtin_amdgcn_mfma_f32_16x16x32_bf16(af, wf2, acc[mt][2], 0,0,0);
        acc[mt][3] = __builtin_amdgcn_mfma_f32_16x16x32_bf16(af, wf3, acc[mt][3], 0,0,0);
      }
    }
  }
  __syncthreads();   // wlds dead; elds aliases it from here

  // ---- q from precomputed Pq: channels ch0 = 16w+c16, ch1 = ch0+64 ----
  const int chA = w*16 + c16;
  float qv[2][4];
  {
    const float* q0 = Pq + ((size_t)b*COx + chA)*NPTS + n0;
    const float* q1 = Pq + ((size_t)b*COx + chA + 64)*NPTS + n0;
    float2 qa = *(const float2*)(q0 + 2*g);
    float2 qb = *(const float2*)(q0 + 8 + 2*g);
    float2 qc = *(const float2*)(q1 + 2*g);
    float2 qd = *(const float2*)(q1 + 8 + 2*g);
    qv[0][0]=qa.x; qv[0][1]=qa.y; qv[0][2]=qb.x; qv[0][3]=qb.y;
    qv[1][0]=qc.x; qv[1][1]=qc.y; qv[1][2]=qd.x; qv[1][3]=qd.y;
  }
  float bkv0 = bKV[chA], bkv1 = bKV[chA + 64];
  float bvv0 = bKV[128 + chA], bvv1 = bKV[128 + chA + 64];

  // ---- 2-phase epilogue: dump acc -> elds (bf16), softmax over K=9, PV, store ----
#pragma unroll
  for (int p = 0; p < 2; p++){
#pragma unroll
    for (int mtl = 0; mtl < 5; mtl++){
      int mt = 4*p + mtl;
      int colb = 16*mt + 4*g - 64*p;        // window offset for reg 0
#pragma unroll
      for (int j = 0; j < 4; j++){
#pragma unroll
        for (int r2 = 0; r2 < 2; r2++){
          unsigned pk = (unsigned)f2bf(acc[mt][j][2*r2]) | ((unsigned)f2bf(acc[mt][j][2*r2+1]) << 16);
          *(unsigned*)&elds[w][j][c16][colb + 2*r2] = pk;
        }
      }
    }
    __syncthreads();

#pragma unroll
    for (int h = 0; h < 2; h++){
      float bk_ = h ? bkv1 : bkv0;
      float bv_ = h ? bvv1 : bvv0;
      float o2[2];
#pragma unroll
      for (int t = 0; t < 2; t++){
        int nloc = 8*p + 2*g + t;
        int cbase = nloc*KW - 64*p;
        float qq = qv[h][2*p + t];
        float sc[KW];
        float mx = -1e30f;
#pragma unroll
        for (int k = 0; k < KW; k++){
          float kf = bf2f(elds[w][h][c16][cbase + k]) + bk_;
          float s_ = qq * kf;
          sc[k] = s_;
          mx = fmaxf(mx, s_);
        }
        float den = 0.f, num = 0.f;
#pragma unroll
        for (int k = 0; k < KW; k++){
          float e = __expf(sc[k] - mx);
          den += e;
          num += e * (bf2f(elds[w][2+h][c16][cbase + k]) + bv_);
        }
        o2[t] = num / den;
      }
      int ch = chA + 64*h;
      *(float2*)&out_local[((size_t)(b*COx + ch))*NPTS + n0 + 8*p + 2*g] = make_float2(o2[0], o2[1]);
    }
    __syncthreads();
  }
}

// ---------------- conv GEMM, I=256 (concat x_row|out_local), R=256 -> two outputs ----------------
__global__ __launch_bounds__(256) void k_conv2x(const float* __restrict__ in0, const float* __restrict__ in1,
    const float* __restrict__ WT, const float* __restrict__ bias,
    float* __restrict__ out0, float* __restrict__ out1)
{
  const int b  = blockIdx.y;
  const int n0 = blockIdx.x * 40;
  const int tid = threadIdx.x;
  __shared__ float tile[256][40];
  for (int idx = tid; idx < 256*40; idx += 256){
    int i = idx / 40; int cc = idx - i*40;
    const float* src = (i < 128) ? (in0 + ((size_t)b*128 + i)*NPTS)
                                 : (in1 + ((size_t)b*128 + (i-128))*NPTS);
    tile[i][cc] = src[n0 + cc];
  }
  __syncthreads();
  const int r = tid;
  float acc[40];
  float bb = bias[r];
#pragma unroll
  for (int j = 0; j < 40; j++) acc[j] = bb;
#pragma unroll 4
  for (int i = 0; i < 256; i++){
    float w = WT[i*256 + r];
#pragma unroll
    for (int j = 0; j < 40; j++) acc[j] += w * tile[i][j];
  }
  float* dst = (r < 128) ? (out0 + ((size_t)b*128 + r)*NPTS + n0)
                         : (out1 + ((size_t)b*128 + (r-128))*NPTS + n0);
#pragma unroll
  for (int j = 0; j < 40; j++) dst[j] = acc[j];
}

// ---------------- conv GEMM, I=128, R=128 ----------------
__global__ __launch_bounds__(256) void k_conv1x(const float* __restrict__ in,
    const float* __restrict__ WT, const float* __restrict__ bias, float* __restrict__ out)
{
  const int b  = blockIdx.y;
  const int n0 = blockIdx.x * 40;
  const int tid = threadIdx.x;
  __shared__ float tile[128][40];
  for (int idx = tid; idx < 128*40; idx += 256){
    int i = idx / 40; int cc = idx - i*40;
    tile[i][cc] = in[((size_t)b*128 + i)*NPTS + n0 + cc];
  }
  __syncthreads();
  const int r = tid & 127;
  const int j0 = (tid >> 7) * 20;
  float acc[20];
  float bb = bias[r];
#pragma unroll
  for (int j = 0; j < 20; j++) acc[j] = bb;
#pragma unroll 4
  for (int i = 0; i < 128; i++){
    float w = WT[i*128 + r];
#pragma unroll
    for (int j = 0; j < 20; j++) acc[j] += w * tile[i][j0 + j];
  }
  float* dst = out + ((size_t)b*128 + r)*NPTS + n0 + j0;
#pragma unroll
  for (int j = 0; j < 20; j++) dst[j] = acc[j];
}

// ---------------- per-(b,c) stats over N=2000 ----------------
__global__ __launch_bounds__(256) void k_cstats(const float* __restrict__ x,
    float* __restrict__ csum, float* __restrict__ csumsq){
  int bc = blockIdx.x;
  const float4* p = (const float4*)(x + (size_t)bc * NPTS);
  float s = 0.f, ss = 0.f;
  for (int idx = threadIdx.x; idx < NPTS/4; idx += 256){
    float4 v = p[idx];
    s  += v.x + v.y + v.z + v.w;
    ss += v.x*v.x + v.y*v.y + v.z*v.z + v.w*v.w;
  }
  __shared__ float rs[256], rss[256];
  rs[threadIdx.x] = s; rss[threadIdx.x] = ss;
  __syncthreads();
  for (int off = 128; off > 0; off >>= 1){
    if (threadIdx.x < off){ rs[threadIdx.x] += rs[threadIdx.x+off]; rss[threadIdx.x] += rss[threadIdx.x+off]; }
    __syncthreads();
  }
  if (threadIdx.x == 0){ csum[bc] = rs[0]; csumsq[bc] = rss[0]; }
}

__global__ void k_cscale(const float* __restrict__ csum, const float* __restrict__ csumsq,
                         float* __restrict__ cm, float* __restrict__ cs){
  int c = threadIdx.x;  // 0..127
  float vl[NB], ml[NB];
  float V = 0.f;
  for (int b = 0; b < NB; b++){
    int bc = b*COx + c;
    float m = csum[bc] * (1.f/(float)NPTS);
    float v = csumsq[bc] * (1.f/(float)NPTS) - m*m;
    ml[b] = m; vl[b] = v;
    V += v / (v + 1e-5f);
  }
  V *= (1.f/(float)NB);
  float bs = rsqrtf(V + 1e-5f);
  for (int b = 0; b < NB; b++){
    int bc = b*COx + c;
    cm[bc] = ml[b];
    cs[bc] = rsqrtf(vl[b] + 1e-5f) * bs;
  }
}

// out = relu((c - m)*s) + add1 [+ add2]
__global__ __launch_bounds__(256) void k_normadd(const float* __restrict__ cbuf,
    const float* __restrict__ add1, const float* __restrict__ add2,
    const float* __restrict__ cm, const float* __restrict__ cs, float* __restrict__ out){
  int bc = blockIdx.x;
  float m = cm[bc], s = cs[bc];
  const float4* pc = (const float4*)(cbuf + (size_t)bc*NPTS);
  const float4* p1 = (const float4*)(add1 + (size_t)bc*NPTS);
  const float4* p2 = add2 ? (const float4*)(add2 + (size_t)bc*NPTS) : nullptr;
  float4* po = (float4*)(out + (size_t)bc*NPTS);
  for (int idx = threadIdx.x; idx < NPTS/4; idx += 256){
    float4 v = pc[idx], a = p1[idx];
    float4 r;
    r.x = fmaxf((v.x - m)*s, 0.f) + a.x;
    r.y = fmaxf((v.y - m)*s, 0.f) + a.y;
    r.z = fmaxf((v.z - m)*s, 0.f) + a.z;
    r.w = fmaxf((v.w - m)*s, 0.f) + a.w;
    if (p2){ float4 a2 = p2[idx]; r.x += a2.x; r.y += a2.y; r.z += a2.z; r.w += a2.w; }
    po[idx] = r;
  }
}

// o3 = relu(norm(c3)+x1); t = x_row + g*o3; out = 0.5*(t + mean_c t)
__global__ __launch_bounds__(256) void k_final(const float* __restrict__ c3, const float* __restrict__ x1,
    const float* __restrict__ x_row, const float* __restrict__ cm, const float* __restrict__ cs,
    const float* __restrict__ gamma1, float* __restrict__ out)
{
  const int b  = blockIdx.y;
  const int n0 = blockIdx.x * 50;
  const int tid = threadIdx.x;
  const float g = gamma1[0];
  __shared__ float tt[128][50];
  __shared__ float part[4][50];
  for (int idx = tid; idx < 128*50; idx += 256){
    int c = idx / 50; int j = idx - c*50;
    size_t off = ((size_t)b*COx + c)*NPTS + n0 + j;
    float o3 = fmaxf((c3[off] - cm[b*COx + c]) * cs[b*COx + c] + x1[off], 0.f);
    tt[c][j] = x_row[off] + g * o3;
  }
  __syncthreads();
  if (tid < 200){
    int gg = tid / 50, j = tid - gg*50;
    float s = 0.f;
    for (int c = gg*32; c < gg*32 + 32; c++) s += tt[c][j];
    part[gg][j] = s;
  }
  __syncthreads();
  for (int idx = tid; idx < 128*50; idx += 256){
    int c = idx / 50; int j = idx - c*50;
    float mean = (part[0][j] + part[1][j] + part[2][j] + part[3][j]) * (1.f/128.f);
    out[((size_t)b*COx + c)*NPTS + n0 + j] = 0.5f * (tt[c][j] + mean);
  }
}

extern "C" void kernel_launch(void* const* d_in, const int* in_sizes, int n_in,
                              void* d_out, int out_size, void* d_ws, size_t ws_size,
                              hipStream_t stream){
  (void)in_sizes; (void)n_in; (void)out_size; (void)ws_size;
  const float* x_row   = (const float*)d_in[0];
  const float* x_local = (const float*)d_in[1];
  const float* w_att1  = (const float*)d_in[2];
  const float* b_att1  = (const float*)d_in[3];
  const float* wq      = (const float*)d_in[4];
  const float* bq      = (const float*)d_in[5];
  const float* wk      = (const float*)d_in[6];
  const float* bk      = (const float*)d_in[7];
  const float* wv      = (const float*)d_in[8];
  const float* bv      = (const float*)d_in[9];
  const float* w_right = (const float*)d_in[10];
  const float* b_right = (const float*)d_in[11];
  const float* w_l1    = (const float*)d_in[12];
  const float* b_l1    = (const float*)d_in[13];
  const float* w_l2    = (const float*)d_in[14];
  const float* b_l2    = (const float*)d_in[15];
  const float* w_l3    = (const float*)d_in[16];
  const float* b_l3    = (const float*)d_in[17];
  const float* gamma1  = (const float*)d_in[18];
  float* out = (float*)d_out;

  float*  ws     = (float*)d_ws;
  float*  sum    = ws;              // 4096
  float*  sumsq  = ws + 4096;       // 4096
  float*  mArr   = ws + 8192;       // 4096
  float*  sArr   = ws + 12288;      // 4096
  ushort* Wf     = (ushort*)(ws + 16384);  // 65536 ushort = 32768 floats
  float*  bKV    = ws + 49152;      // 256
  float*  wqT    = ws + 49408;      // 16384
  float*  WT2    = ws + 65792;      // 65536
  float*  bias2  = ws + 131328;     // 256
  float*  WT3    = ws + 131584;     // 16384
  float*  WT4    = ws + 147968;     // 16384
  float*  csum   = ws + 164352;     // 2048
  float*  csumsq = ws + 166400;     // 2048
  float*  cm     = ws + 168448;     // 2048
  float*  cs     = ws + 170496;     // 2048
  float*  P0 = ws + 262144;         // 4,096,000 each
  float*  P1 = P0 + 4096000;
  float*  P2 = P1 + 4096000;
  float*  P3 = P2 + 4096000;

  // stats + weight prep
  k_xstats  <<<4096, 256, 0, stream>>>(x_local, sum, sumsq);
  k_xscale  <<<1, 256, 0, stream>>>(sum, sumsq, mArr, sArr);
  k_prep_kv <<<256, 256, 0, stream>>>(w_att1, wk, wv, b_att1, bk, bv, Wf, bKV);
  k_transpose<<<64, 256, 0, stream>>>(wq,   wqT, 128, 128);
  k_prep2   <<<256, 256, 0, stream>>>(w_right, w_l1, b_right, b_l1, WT2, bias2);
  k_transpose<<<64, 256, 0, stream>>>(w_l2, WT3, 128, 128);
  k_transpose<<<64, 256, 0, stream>>>(w_l3, WT4, 128, 128);

  // q = wq . x_row + bq  -> P1 (read by attn, overwritten later by conv2x)
  k_conv1x<<<dim3(NPTS/40, NB), 256, 0, stream>>>(x_row, wqT, bq, P1);

  // fused MFMA attention -> out_local (P0)
  k_attn_mfma<<<dim3(125, NB), 256, 0, stream>>>(x_local, mArr, sArr, Wf, bKV, P1, P0);

  // x1 (P1), c1 (P2)
  k_conv2x<<<dim3(NPTS/40, NB), 256, 0, stream>>>(x_row, P0, WT2, bias2, P1, P2);
  k_cstats<<<NB*COx, 256, 0, stream>>>(P2, csum, csumsq);
  k_cscale<<<1, 128, 0, stream>>>(csum, csumsq, cm, cs);
  // o1 (P3) = relu(norm(c1)) + x1
  k_normadd<<<NB*COx, 256, 0, stream>>>(P2, P1, nullptr, cm, cs, P3);

  // c2 (P0) = w_l2 . o1
  k_conv1x<<<dim3(NPTS/40, NB), 256, 0, stream>>>(P3, WT3, b_l2, P0);
  k_cstats<<<NB*COx, 256, 0, stream>>>(P0, csum, csumsq);
  k_cscale<<<1, 128, 0, stream>>>(csum, csumsq, cm, cs);
  // o2 (P2) = relu(norm(c2)) + o1 + x1
  k_normadd<<<NB*COx, 256, 0, stream>>>(P0, P3, P1, cm, cs, P2);

  // c3 (P3) = w_l3 . o2
  k_conv1x<<<dim3(NPTS/40, NB), 256, 0, stream>>>(P2, WT4, b_l3, P3);
  k_cstats<<<NB*COx, 256, 0, stream>>>(P3, csum, csumsq);
  k_cscale<<<1, 128, 0, stream>>>(csum, csumsq, cm, cs);

  // final: o3 = relu(norm(c3)+x1); out = 0.5*((x_row + g*o3) + mean_c(...))
  k_final<<<dim3(NPTS/50, NB), 256, 0, stream>>>(P3, P1, x_row, cm, cs, gamma1, out);
}

// Round 4
// 404.465 us; speedup vs baseline: 2.8467x; 1.3178x over previous
//
#include <hip/hip_runtime.h>
#include <math.h>

#define NB    16
#define CIx   256
#define COx   128
#define NPTS  2000
#define KW    9
#define NKx   18000   // NPTS*KW
#define NTIL  25      // n tiles of 80 for mconv

typedef short bf16x8 __attribute__((ext_vector_type(8)));
typedef float f32x4  __attribute__((ext_vector_type(4)));

__device__ __forceinline__ ushort f2bf(float f){
  unsigned u = __builtin_bit_cast(unsigned, f);
  u = (u + 0x7fffu + ((u>>16)&1u)) >> 16;
  return (ushort)u;
}
__device__ __forceinline__ float bf2f(ushort h){
  unsigned u = ((unsigned)h)<<16;
  return __builtin_bit_cast(float, u);
}

// ---------------- stats over x_local: per (b,i) sum/sumsq over 18000 ----------------
__global__ __launch_bounds__(256) void k_xstats(const float* __restrict__ xl,
    float* __restrict__ sum, float* __restrict__ sumsq){
  int bi = blockIdx.x;                       // b*256 + i
  const float4* p = (const float4*)(xl + (size_t)bi * NKx);
  float s = 0.f, ss = 0.f;
  for (int idx = threadIdx.x; idx < NKx/4; idx += 256){
    float4 v = p[idx];
    s  += v.x + v.y + v.z + v.w;
    ss += v.x*v.x + v.y*v.y + v.z*v.z + v.w*v.w;
  }
  __shared__ float rs[256], rss[256];
  rs[threadIdx.x] = s; rss[threadIdx.x] = ss;
  __syncthreads();
  for (int off = 128; off > 0; off >>= 1){
    if (threadIdx.x < off){ rs[threadIdx.x] += rs[threadIdx.x+off]; rss[threadIdx.x] += rss[threadIdx.x+off]; }
    __syncthreads();
  }
  if (threadIdx.x == 0){ sum[bi] = rs[0]; sumsq[bi] = rss[0]; }
}

// inorm(1e-3) + bnorm(1e-5) collapse: per (b,i) m and combined scale s
__global__ void k_xscale(const float* __restrict__ sum, const float* __restrict__ sumsq,
                         float* __restrict__ mOut, float* __restrict__ sOut){
  int i = threadIdx.x;                       // channel 0..255
  float vl[NB], ml[NB];
  float V = 0.f;
  for (int b = 0; b < NB; b++){
    int bi = b*CIx + i;
    float m = sum[bi] * (1.f/(float)NKx);
    float v = sumsq[bi] * (1.f/(float)NKx) - m*m;
    ml[b] = m; vl[b] = v;
    V += v / (v + 1e-3f);
  }
  V *= (1.f/(float)NB);
  float bs = rsqrtf(V + 1e-5f);
  for (int b = 0; b < NB; b++){
    int bi = b*CIx + i;
    mOut[bi] = ml[b];
    sOut[bi] = rsqrtf(vl[b] + 1e-3f) * bs;
  }
}

// ---- fold wk@w_att1 / wv@w_att1 into Wf[r][i] bf16 (r<128:K, r>=128:V), row-major ----
__global__ void k_prep_kv(const float* __restrict__ w_att1, const float* __restrict__ wk,
                          const float* __restrict__ wv, const float* __restrict__ b_att1,
                          const float* __restrict__ bk, const float* __restrict__ bv,
                          ushort* __restrict__ Wf, float* __restrict__ bKV){
  int r = blockIdx.x;   // 0..255
  int i = threadIdx.x;  // 0..255
  const float* wr = (r < 128) ? (wk + r*128) : (wv + (r-128)*128);
  float acc = 0.f;
  for (int c = 0; c < 128; c++) acc += wr[c] * w_att1[c*CIx + i];
  Wf[r*256 + i] = f2bf(acc);
  if (i == 0){
    float bacc = (r < 128) ? bk[r] : bv[r-128];
    for (int c = 0; c < 128; c++) bacc += wr[c] * b_att1[c];
    bKV[r] = bacc;
  }
}

// ---- pack conv weights to bf16 [r][i] + stacked bias2 ----
__global__ void k_prepW(const float* __restrict__ wq, const float* __restrict__ w_right,
                        const float* __restrict__ w_l1, const float* __restrict__ w_l2,
                        const float* __restrict__ w_l3, const float* __restrict__ b_right,
                        const float* __restrict__ b_l1,
                        ushort* __restrict__ Wq, ushort* __restrict__ W2,
                        ushort* __restrict__ W3, ushort* __restrict__ W4,
                        float* __restrict__ bias2){
  int idx = blockIdx.x*256 + threadIdx.x;
  if (idx < 16384){ Wq[idx] = f2bf(wq[idx]); return; }
  idx -= 16384;
  if (idx < 65536){
    int r = idx >> 8, i = idx & 255;
    W2[idx] = f2bf(r < 128 ? w_right[r*256+i] : w_l1[(r-128)*256+i]);
    return;
  }
  idx -= 65536;
  if (idx < 16384){ W3[idx] = f2bf(w_l2[idx]); return; }
  idx -= 16384;
  if (idx < 16384){ W4[idx] = f2bf(w_l3[idx]); return; }
  idx -= 16384;
  if (idx < 256) bias2[idx] = (idx < 128) ? b_right[idx] : b_l1[idx-128];
}

// ---------------- fused MFMA attention ----------------
// D[colx][r] = sum_i xnorm[i][col0+colx] * Wf[r][i]   (C^T orientation)
__global__ __launch_bounds__(256,2) void k_attn_mfma(
    const float* __restrict__ xl,
    const float* __restrict__ mArr, const float* __restrict__ sArr,
    const ushort* __restrict__ Wf, const float* __restrict__ bKV,
    const float* __restrict__ Pq,
    float* __restrict__ out_local)
{
  const int b   = blockIdx.y;
  const int n0  = blockIdx.x * 16;
  const int col0 = n0 * KW;                 // 144 * blockIdx.x
  const int tid = threadIdx.x;
  const int w   = tid >> 6;
  const int lane = tid & 63;
  const int c16 = lane & 15, g = lane >> 4;

  __shared__ ushort smem_u[20992];          // wlds then aliased as elds
  __shared__ float obuf[128*17];            // coalescing buffer for out_local
  ushort* wlds = smem_u;
  ushort (*elds)[4][16][82] = (ushort (*)[4][16][82])smem_u;

  f32x4 acc[9][4];
#pragma unroll
  for (int mt = 0; mt < 9; mt++)
#pragma unroll
    for (int j = 0; j < 4; j++) acc[mt][j] = (f32x4)0.f;

  const int ct0 = w, ct1 = w + 4, ct2 = w + 8, ct3 = w + 12;
  const int sg_l = ((c16 & 3) << 2) | (c16 >> 2);

  for (int half = 0; half < 2; half++){
    __syncthreads();
    {
      const size_t xb = (size_t)b*CIx*NKx + (size_t)(half*128)*NKx + col0;
      const float* mB = mArr + b*CIx + half*128;
      const float* sB = sArr + b*CIx + half*128;
#pragma unroll
      for (int kk = 0; kk < 9; kk++){
        int flat = tid + 256*kk;            // 0..2303
        int il   = flat / 36;               // i-pair 0..63
        int c4   = flat - il*36;            // float4 col group 0..35
        int i_l  = il*2;
        int col  = c4*4;
        const float* gp = xl + xb + (size_t)i_l*NKx + col;
        float4 r0 = *(const float4*)gp;
        float4 r1 = *(const float4*)(gp + NKx);
        float m0 = mB[i_l],   s0 = sB[i_l];
        float m1 = mB[i_l+1], s1 = sB[i_l+1];
        int sp  = i_l >> 5;
        int g_  = (i_l >> 3) & 3;
        int io2 = il & 3;
        int mt  = col >> 4;
        unsigned* dstb = (unsigned*)wlds + ((sp*9 + mt)*4 + g_)*64 + io2;
        float a0[4] = {r0.x, r0.y, r0.z, r0.w};
        float a1[4] = {r1.x, r1.y, r1.z, r1.w};
#pragma unroll
        for (int j = 0; j < 4; j++){
          int cj = (col + j) & 15;
          int sg = ((cj & 3) << 2) | (cj >> 2);
          float v0 = fmaxf((a0[j] - m0)*s0, 0.f);
          float v1 = fmaxf((a1[j] - m1)*s1, 0.f);
          dstb[sg*4] = (unsigned)f2bf(v0) | ((unsigned)f2bf(v1) << 16);
        }
      }
    }
    __syncthreads();
#pragma unroll
    for (int sp = 0; sp < 4; sp++){
      int s = half*4 + sp;
      bf16x8 wf0 = *(const bf16x8*)(Wf + (ct0*16 + c16)*256 + s*32 + g*8);
      bf16x8 wf1 = *(const bf16x8*)(Wf + (ct1*16 + c16)*256 + s*32 + g*8);
      bf16x8 wf2 = *(const bf16x8*)(Wf + (ct2*16 + c16)*256 + s*32 + g*8);
      bf16x8 wf3 = *(const bf16x8*)(Wf + (ct3*16 + c16)*256 + s*32 + g*8);
#pragma unroll
      for (int mt = 0; mt < 9; mt++){
        bf16x8 af = *(const bf16x8*)(wlds + ((sp*9 + mt)*4 + g)*128 + sg_l*8);
        acc[mt][0] = __builtin_amdgcn_mfma_f32_16x16x32_bf16(af, wf0, acc[mt][0], 0,0,0);
        acc[mt][1] = __builtin_amdgcn_mfma_f32_16x16x32_bf16(af, wf1, acc[mt][1], 0,0,0);
        acc[mt][2] = __builtin_amdgcn_mfma_f32_16x16x32_bf16(af, wf2, acc[mt][2], 0,0,0);
        acc[mt][3] = __builtin_amdgcn_mfma_f32_16x16x32_bf16(af, wf3, acc[mt][3], 0,0,0);
      }
    }
  }
  __syncthreads();   // wlds dead; elds aliases it from here

  const int chA = w*16 + c16;
  float qv[2][4];
  {
    const float* q0 = Pq + ((size_t)b*COx + chA)*NPTS + n0;
    const float* q1 = Pq + ((size_t)b*COx + chA + 64)*NPTS + n0;
    float2 qa = *(const float2*)(q0 + 2*g);
    float2 qb = *(const float2*)(q0 + 8 + 2*g);
    float2 qc = *(const float2*)(q1 + 2*g);
    float2 qd = *(const float2*)(q1 + 8 + 2*g);
    qv[0][0]=qa.x; qv[0][1]=qa.y; qv[0][2]=qb.x; qv[0][3]=qb.y;
    qv[1][0]=qc.x; qv[1][1]=qc.y; qv[1][2]=qd.x; qv[1][3]=qd.y;
  }
  float bkv0 = bKV[chA], bkv1 = bKV[chA + 64];
  float bvv0 = bKV[128 + chA], bvv1 = bKV[128 + chA + 64];

#pragma unroll
  for (int p = 0; p < 2; p++){
#pragma unroll
    for (int mtl = 0; mtl < 5; mtl++){
      int mt = 4*p + mtl;
      int colb = 16*mt + 4*g - 64*p;
#pragma unroll
      for (int j = 0; j < 4; j++){
#pragma unroll
        for (int r2 = 0; r2 < 2; r2++){
          unsigned pk = (unsigned)f2bf(acc[mt][j][2*r2]) | ((unsigned)f2bf(acc[mt][j][2*r2+1]) << 16);
          *(unsigned*)&elds[w][j][c16][colb + 2*r2] = pk;
        }
      }
    }
    __syncthreads();

#pragma unroll
    for (int h = 0; h < 2; h++){
      float bk_ = h ? bkv1 : bkv0;
      float bv_ = h ? bvv1 : bvv0;
      int ch = chA + 64*h;
#pragma unroll
      for (int t = 0; t < 2; t++){
        int nloc = 8*p + 2*g + t;
        int cbase = nloc*KW - 64*p;
        float qq = qv[h][2*p + t];
        float sc[KW];
        float mx = -1e30f;
#pragma unroll
        for (int k = 0; k < KW; k++){
          float kf = bf2f(elds[w][h][c16][cbase + k]) + bk_;
          float s_ = qq * kf;
          sc[k] = s_;
          mx = fmaxf(mx, s_);
        }
        float den = 0.f, num = 0.f;
#pragma unroll
        for (int k = 0; k < KW; k++){
          float e = __expf(sc[k] - mx);
          den += e;
          num += e * (bf2f(elds[w][2+h][c16][cbase + k]) + bv_);
        }
        obuf[ch*17 + nloc] = num / den;
      }
    }
    __syncthreads();
  }

  // coalesced store: 2 threads per channel, full 64B lines
  {
    int ch = tid >> 1, q8 = tid & 1;
    float4 v0, v1;
    int base = ch*17 + q8*8;
    v0.x = obuf[base+0]; v0.y = obuf[base+1]; v0.z = obuf[base+2]; v0.w = obuf[base+3];
    v1.x = obuf[base+4]; v1.y = obuf[base+5]; v1.z = obuf[base+6]; v1.w = obuf[base+7];
    float* dst = out_local + ((size_t)(b*COx + ch))*NPTS + n0 + q8*8;
    *(float4*)dst = v0;
    *(float4*)(dst+4) = v1;
  }
}

// ---------------- generic MFMA conv1x1 over n-tiles of 80 ----------------
// MODE 0: q (I=128,R=128): in = inA raw
// MODE 1: conv2x (I=256,R=256): in = concat(inA,inB); out0=x1(r<128), out1=c1; stats on c1
// MODE 2: c2 (I=128): in = relu((inA-nm)*nsc)+inB; side-write uout = in+inB; stats
// MODE 3: c3 (I=128): in = relu((inA-nm)*nsc)+inB; stats
template<int MODE>
__global__ __launch_bounds__(256) void k_mconv(
    const float* __restrict__ inA, const float* __restrict__ inB,
    const ushort* __restrict__ Wc, const float* __restrict__ bias,
    const float* __restrict__ nm, const float* __restrict__ nsc,
    float* __restrict__ out0, float* __restrict__ out1,
    float* __restrict__ uout, float* __restrict__ pstat)
{
  constexpr int IC = (MODE==1) ? 256 : 128;
  constexpr int RC = (MODE==1) ? 256 : 128;
  constexpr int NS = IC/32;
  constexpr int JW = RC/64;                 // ct per wave (4 or 2)
  constexpr int PHASES = RC/128;
  constexpr bool STATS = (MODE >= 1);
  constexpr int SPH = (MODE==1) ? 1 : 0;

  const int b = blockIdx.y, bx = blockIdx.x;
  const int n0 = bx*80;
  const int tid = threadIdx.x;
  const int w = tid>>6, lane = tid&63;
  const int c16 = lane&15, g = lane>>4;

  __shared__ ushort smem[21504];            // 43008B: staging (<=40960B) then dump f32 [128][84]

  // ---- stage input tile [IC][80] -> bf16 frag-linear ----
  {
    constexpr int TOT = (IC/2)*20;
    const float* srcA = inA + (size_t)b*128*NPTS;
    const float* srcB = inB ? (inB + (size_t)b*128*NPTS) : nullptr;
    for (int idx = tid; idx < TOT; idx += 256){
      int pr = idx/20, c4 = idx - 20*pr;
      int i = pr*2;
      int cc = n0 + 4*c4;
      float4 va, vb;
      if (MODE == 0){
        const float* base = srcA + (size_t)i*NPTS + cc;
        va = *(const float4*)base;
        vb = *(const float4*)(base + NPTS);
      } else if (MODE == 1){
        const float* base = (i < 128) ? (srcA + (size_t)i*NPTS + cc)
                                      : (srcB + (size_t)(i-128)*NPTS + cc);
        va = *(const float4*)base;
        vb = *(const float4*)(base + NPTS);
      } else {
        const float* pa = srcA + (size_t)i*NPTS + cc;
        const float* pb = srcB + (size_t)i*NPTS + cc;
        float4 ca = *(const float4*)pa, cb = *(const float4*)(pa+NPTS);
        float4 aa = *(const float4*)pb, ab = *(const float4*)(pb+NPTS);
        float m0 = nm[b*128+i],   s0 = nsc[b*128+i];
        float m1 = nm[b*128+i+1], s1 = nsc[b*128+i+1];
        va.x = fmaxf((ca.x-m0)*s0,0.f)+aa.x; va.y = fmaxf((ca.y-m0)*s0,0.f)+aa.y;
        va.z = fmaxf((ca.z-m0)*s0,0.f)+aa.z; va.w = fmaxf((ca.w-m0)*s0,0.f)+aa.w;
        vb.x = fmaxf((cb.x-m1)*s1,0.f)+ab.x; vb.y = fmaxf((cb.y-m1)*s1,0.f)+ab.y;
        vb.z = fmaxf((cb.z-m1)*s1,0.f)+ab.z; vb.w = fmaxf((cb.w-m1)*s1,0.f)+ab.w;
        if (MODE == 2){
          float4 u0, u1;
          u0.x = va.x+aa.x; u0.y = va.y+aa.y; u0.z = va.z+aa.z; u0.w = va.w+aa.w;
          u1.x = vb.x+ab.x; u1.y = vb.y+ab.y; u1.z = vb.z+ab.z; u1.w = vb.w+ab.w;
          *(float4*)(uout + ((size_t)(b*128+i))*NPTS + cc) = u0;
          *(float4*)(uout + ((size_t)(b*128+i+1))*NPTS + cc) = u1;
        }
      }
      int sp = i>>5, g_ = (i>>3)&3, io2 = (i>>1)&3;
      int mt = c4>>2;
      unsigned* dstb = (unsigned*)smem + ((sp*5 + mt)*4 + g_)*64 + io2;
      float a0[4] = {va.x, va.y, va.z, va.w};
      float a1[4] = {vb.x, vb.y, vb.z, vb.w};
#pragma unroll
      for (int j = 0; j < 4; j++){
        int cj = (4*c4 + j) & 15;
        int sg = ((cj & 3) << 2) | (cj >> 2);
        dstb[sg*4] = (unsigned)f2bf(a0[j]) | ((unsigned)f2bf(a1[j]) << 16);
      }
    }
  }
  __syncthreads();

  // ---- MFMA ----
  const int sgl = ((c16 & 3) << 2) | (c16 >> 2);
  f32x4 acc[5][JW];
#pragma unroll
  for (int mt = 0; mt < 5; mt++)
#pragma unroll
    for (int j = 0; j < JW; j++) acc[mt][j] = (f32x4)0.f;

  for (int s = 0; s < NS; s++){
    bf16x8 wf[JW];
#pragma unroll
    for (int j = 0; j < JW; j++)
      wf[j] = *(const bf16x8*)(Wc + ((w + 4*j)*16 + c16)*IC + s*32 + g*8);
#pragma unroll
    for (int mt = 0; mt < 5; mt++){
      bf16x8 af = *(const bf16x8*)(smem + ((s*5 + mt)*4 + g)*128 + sgl*8);
#pragma unroll
      for (int j = 0; j < JW; j++)
        acc[mt][j] = __builtin_amdgcn_mfma_f32_16x16x32_bf16(af, wf[j], acc[mt][j], 0,0,0);
    }
  }

  // ---- bias + dump (coalesced) + fused stats partials ----
  float* dl = (float*)smem;
#pragma unroll
  for (int ph = 0; ph < PHASES; ph++){
    __syncthreads();
    float st_s[2], st_ss[2];
#pragma unroll
    for (int jj = 0; jj < 2; jj++){
      int j = ph*2 + jj;
      int ct = w + 4*j;
      int rl = (ct & 7)*16 + c16;
      float bb = bias[ct*16 + c16];
      float s = 0.f, ss = 0.f;
#pragma unroll
      for (int mt = 0; mt < 5; mt++){
        f32x4 v = acc[mt][j];
        float4 vv;
        vv.x = v[0]+bb; vv.y = v[1]+bb; vv.z = v[2]+bb; vv.w = v[3]+bb;
        *(float4*)&dl[rl*84 + mt*16 + 4*g] = vv;
        s  += vv.x + vv.y + vv.z + vv.w;
        ss += vv.x*vv.x + vv.y*vv.y + vv.z*vv.z + vv.w*vv.w;
      }
      st_s[jj] = s; st_ss[jj] = ss;
    }
    if (STATS && ph == SPH){
#pragma unroll
      for (int jj = 0; jj < 2; jj++){
        float s = st_s[jj], ss = st_ss[jj];
        s += __shfl_xor(s, 16); ss += __shfl_xor(ss, 16);
        s += __shfl_xor(s, 32); ss += __shfl_xor(ss, 32);
        if (g == 0){
          int ct = w + 4*(ph*2 + jj);
          int rl = (ct & 7)*16 + c16;
          size_t pb = (((size_t)b*NTIL + bx)*128 + rl)*2;
          pstat[pb]   = s;
          pstat[pb+1] = ss;
        }
      }
    }
    __syncthreads();
    float* dst = ph ? out1 : out0;
#pragma unroll
    for (int kk = 0; kk < 10; kk++){
      int idx = kk*256 + tid;
      int r = idx/20, c4 = idx - 20*r;
      *(float4*)(dst + ((size_t)(b*128 + r))*NPTS + n0 + 4*c4) = *(float4*)&dl[r*84 + 4*c4];
    }
  }
}

// ---- reduce pstat -> per-(b,c) m and combined inorm(1e-5)+bnorm scale ----
__global__ void k_red(const float* __restrict__ pstat, float* __restrict__ cm, float* __restrict__ cs){
  int c = threadIdx.x;  // 0..127
  float ml[NB], vl[NB];
  float V = 0.f;
  for (int b = 0; b < NB; b++){
    float s = 0.f, ss = 0.f;
    for (int t = 0; t < NTIL; t++){
      size_t base = (((size_t)b*NTIL + t)*128 + c)*2;
      s  += pstat[base];
      ss += pstat[base+1];
    }
    float m = s * (1.f/(float)NPTS);
    float v = ss * (1.f/(float)NPTS) - m*m;
    ml[b] = m; vl[b] = v;
    V += v / (v + 1e-5f);
  }
  V *= (1.f/(float)NB);
  float bs = rsqrtf(V + 1e-5f);
  for (int b = 0; b < NB; b++){
    cm[b*COx + c] = ml[b];
    cs[b*COx + c] = rsqrtf(vl[b] + 1e-5f) * bs;
  }
}

// o3 = relu(norm(c3)+x1); t = x_row + g*o3; out = 0.5*(t + mean_c t)
__global__ __launch_bounds__(256) void k_final(const float* __restrict__ c3, const float* __restrict__ x1,
    const float* __restrict__ x_row, const float* __restrict__ cm, const float* __restrict__ cs,
    const float* __restrict__ gamma1, float* __restrict__ out)
{
  const int b  = blockIdx.y;
  const int n0 = blockIdx.x * 50;
  const int tid = threadIdx.x;
  const float g = gamma1[0];
  __shared__ float tt[128][50];
  __shared__ float part[4][50];
  for (int idx = tid; idx < 128*50; idx += 256){
    int c = idx / 50; int j = idx - c*50;
    size_t off = ((size_t)b*COx + c)*NPTS + n0 + j;
    float o3 = fmaxf((c3[off] - cm[b*COx + c]) * cs[b*COx + c] + x1[off], 0.f);
    tt[c][j] = x_row[off] + g * o3;
  }
  __syncthreads();
  if (tid < 200){
    int gg = tid / 50, j = tid - gg*50;
    float s = 0.f;
    for (int c = gg*32; c < gg*32 + 32; c++) s += tt[c][j];
    part[gg][j] = s;
  }
  __syncthreads();
  for (int idx = tid; idx < 128*50; idx += 256){
    int c = idx / 50; int j = idx - c*50;
    float mean = (part[0][j] + part[1][j] + part[2][j] + part[3][j]) * (1.f/128.f);
    out[((size_t)b*COx + c)*NPTS + n0 + j] = 0.5f * (tt[c][j] + mean);
  }
}

extern "C" void kernel_launch(void* const* d_in, const int* in_sizes, int n_in,
                              void* d_out, int out_size, void* d_ws, size_t ws_size,
                              hipStream_t stream){
  (void)in_sizes; (void)n_in; (void)out_size; (void)ws_size;
  const float* x_row   = (const float*)d_in[0];
  const float* x_local = (const float*)d_in[1];
  const float* w_att1  = (const float*)d_in[2];
  const float* b_att1  = (const float*)d_in[3];
  const float* wq      = (const float*)d_in[4];
  const float* bq      = (const float*)d_in[5];
  const float* wk      = (const float*)d_in[6];
  const float* bk      = (const float*)d_in[7];
  const float* wv      = (const float*)d_in[8];
  const float* bv      = (const float*)d_in[9];
  const float* w_right = (const float*)d_in[10];
  const float* b_right = (const float*)d_in[11];
  const float* w_l1    = (const float*)d_in[12];
  const float* b_l1    = (const float*)d_in[13];
  const float* w_l2    = (const float*)d_in[14];
  const float* b_l2    = (const float*)d_in[15];
  const float* w_l3    = (const float*)d_in[16];
  const float* b_l3    = (const float*)d_in[17];
  const float* gamma1  = (const float*)d_in[18];
  float* out = (float*)d_out;

  float*  ws     = (float*)d_ws;
  float*  sum    = ws;                        // 4096
  float*  sumsq  = ws + 4096;                 // 4096
  float*  mArr   = ws + 8192;                 // 4096
  float*  sArr   = ws + 12288;                // 4096
  ushort* Wf     = (ushort*)(ws + 16384);     // 65536 us
  float*  bKV    = ws + 49152;                // 256
  ushort* Wq     = (ushort*)(ws + 49408);     // 16384 us
  ushort* W2     = (ushort*)(ws + 57600);     // 65536 us
  ushort* W3     = (ushort*)(ws + 90368);     // 16384 us
  ushort* W4     = (ushort*)(ws + 98560);     // 16384 us
  float*  bias2  = ws + 106752;               // 256
  float*  cm     = ws + 107008;               // 2048
  float*  cs     = ws + 109056;               // 2048
  float*  pstat  = ws + 111104;               // 102400
  float*  P0 = ws + 262144;                   // 4,096,000 each
  float*  P1 = P0 + 4096000;
  float*  P2 = P1 + 4096000;
  float*  P3 = P2 + 4096000;

  // stats + weight prep
  k_xstats <<<4096, 256, 0, stream>>>(x_local, sum, sumsq);
  k_xscale <<<1, 256, 0, stream>>>(sum, sumsq, mArr, sArr);
  k_prep_kv<<<256, 256, 0, stream>>>(w_att1, wk, wv, b_att1, bk, bv, Wf, bKV);
  k_prepW  <<<450, 256, 0, stream>>>(wq, w_right, w_l1, w_l2, w_l3, b_right, b_l1,
                                     Wq, W2, W3, W4, bias2);

  // q = wq . x_row + bq -> P1
  k_mconv<0><<<dim3(NTIL, NB), 256, 0, stream>>>(x_row, nullptr, Wq, bq,
                                                 nullptr, nullptr, P1, nullptr, nullptr, nullptr);

  // fused MFMA attention -> out_local (P0)
  k_attn_mfma<<<dim3(125, NB), 256, 0, stream>>>(x_local, mArr, sArr, Wf, bKV, P1, P0);

  // x1 (P1), c1 (P2) + stats(c1)
  k_mconv<1><<<dim3(NTIL, NB), 256, 0, stream>>>(x_row, P0, W2, bias2,
                                                 nullptr, nullptr, P1, P2, nullptr, pstat);
  k_red<<<1, 128, 0, stream>>>(pstat, cm, cs);

  // stage o1 = relu(norm(c1))+x1; c2 (P3); u = o1+x1 -> P0; stats(c2)
  k_mconv<2><<<dim3(NTIL, NB), 256, 0, stream>>>(P2, P1, W3, b_l2,
                                                 cm, cs, P3, nullptr, P0, pstat);
  k_red<<<1, 128, 0, stream>>>(pstat, cm, cs);

  // stage o2 = relu(norm(c2))+u; c3 (P2); stats(c3)
  k_mconv<3><<<dim3(NTIL, NB), 256, 0, stream>>>(P3, P0, W4, b_l3,
                                                 cm, cs, P2, nullptr, nullptr, pstat);
  k_red<<<1, 128, 0, stream>>>(pstat, cm, cs);

  // final
  k_final<<<dim3(NPTS/50, NB), 256, 0, stream>>>(P2, P1, x_row, cm, cs, gamma1, out);
}